// Round 1
// baseline (261.222 us; speedup 1.0000x reference)
//
#include <hip/hip_runtime.h>

// CellListNL MIC neighbor predicate, N=4096, rc=5, cell = L*I (diagonal).
// Output layout (single fp32 buffer, concatenated flat in return order):
//   out[0 .. N*N)           : d2_masked[i][j]
//   out[N*N .. N*N + N*N*3) : shift[i][j][c] stored as float (-1/0/1), 0 if not kept
//
// Write-BW-bound: 256 MiB of stores, ~43 us floor at 6.3 TB/s.

constexpr int N_ATOMS = 4096;
constexpr float RC2 = 25.0f;   // rc = 5.0

__global__ __launch_bounds__(256) void cellnl_kernel(
    const float* __restrict__ coord,
    const float* __restrict__ cell,
    float* __restrict__ out)
{
    // cell is L * I; reference's inv(cell) = diag(float32(1/L)) (LU on a
    // diagonal matrix solves 40x=1 exactly as one rounded division).
    const float L   = cell[0];
    const float inv = 1.0f / L;

    const int idx = blockIdx.x * 256 + threadIdx.x;   // N * N/4 threads
    const int i  = idx >> 10;                          // row atom
    const int j0 = (idx & 1023) << 2;                  // first of 4 col atoms

    // frac_i = wrap(coord_i / L): scalar loads, 12B shared by 1024 threads -> cached
    float fix = coord[3 * i + 0] * inv; fix -= floorf(fix);
    float fiy = coord[3 * i + 1] * inv; fiy -= floorf(fiy);
    float fiz = coord[3 * i + 2] * inv; fiz -= floorf(fiz);

    // 4 consecutive j atoms = 12 consecutive floats, 16B-aligned (j0 % 4 == 0)
    const float4* cj = reinterpret_cast<const float4*>(coord + 3 * j0);
    const float4 A = cj[0], B = cj[1], C = cj[2];
    const float jx[4] = {A.x, A.w, B.z, C.y};
    const float jy[4] = {A.y, B.x, B.w, C.z};
    const float jz[4] = {A.z, B.y, C.x, C.w};

    float4 d2v;
    float* d2p = &d2v.x;
    float s[12];

#pragma unroll
    for (int k = 0; k < 4; ++k) {
        float fjx = jx[k] * inv; fjx -= floorf(fjx);
        float fjy = jy[k] * inv; fjy -= floorf(fjy);
        float fjz = jz[k] * inv; fjz -= floorf(fjz);

        // dfrac = frac_j - frac_i; MIC shift = -round_half_even(dfrac)
        float dx = fjx - fix, dy = fjy - fiy, dz = fjz - fiz;
        const float sx = -rintf(dx), sy = -rintf(dy), sz = -rintf(dz);  // v_rndne matches jnp.round
        dx += sx; dy += sy; dz += sz;
        dx *= L; dy *= L; dz *= L;                 // dfrac @ cell, cell diagonal

        const float dist2 = dx * dx + dy * dy + dz * dz;
        const bool keep = (dist2 > 0.0f) && (dist2 < RC2);

        d2p[k]       = keep ? dist2 : 0.0f;
        s[3 * k + 0] = keep ? sx : 0.0f;           // stored as float; harness reads fp32
        s[3 * k + 1] = keep ? sy : 0.0f;
        s[3 * k + 2] = keep ? sz : 0.0f;
    }

    // d2: 16B/lane, wave covers 1KB contiguous
    const size_t base = (size_t)i * N_ATOMS + j0;
    *reinterpret_cast<float4*>(out + base) = d2v;

    // shift: 48 contiguous bytes per lane, 16B-aligned; 3x dwordx4 stores
    float4* shp = reinterpret_cast<float4*>(out + (size_t)N_ATOMS * N_ATOMS + base * 3);
    shp[0] = make_float4(s[0], s[1], s[2],  s[3]);
    shp[1] = make_float4(s[4], s[5], s[6],  s[7]);
    shp[2] = make_float4(s[8], s[9], s[10], s[11]);
}

extern "C" void kernel_launch(void* const* d_in, const int* in_sizes, int n_in,
                              void* d_out, int out_size, void* d_ws, size_t ws_size,
                              hipStream_t stream) {
    const float* coord = (const float*)d_in[0];   // [4096, 3] fp32
    const float* cell  = (const float*)d_in[1];   // [3, 3] fp32, L*I
    float* out = (float*)d_out;                    // 4096^2 + 4096^2*3 fp32

    const int total_threads = N_ATOMS * (N_ATOMS / 4);   // 4,194,304
    const int blocks = total_threads / 256;              // 16,384
    hipLaunchKernelGGL(cellnl_kernel, dim3(blocks), dim3(256), 0, stream,
                       coord, cell, out);
}

// Round 2
// 256.568 us; speedup vs baseline: 1.0181x; 1.0181x over previous
//
#include <hip/hip_runtime.h>

// CellListNL MIC neighbor predicate, N=4096, rc=5, cell = L*I (diagonal).
// Output layout (single fp32 buffer, concatenated flat in return order):
//   out[0 .. N*N)           : d2_masked[i][j]
//   out[N*N .. N*N + N*N*3) : shift[i][j][c] as float (-1/0/1), 0 if not kept
//
// Round 1 lesson: 4-pairs/thread gave per-instruction stride-48 shift stores
// -> ~1 TB/s effective. Now ONE pair per thread:
//   d2   : dword store, lanes stride 4  -> 256 B/wave contiguous
//   shift: dwordx3 store, lanes stride 12 -> 768 B/wave contiguous, 64B-aligned
// Every cache line fully written by a single instruction.

constexpr int N_ATOMS = 4096;
constexpr float RC2 = 25.0f;   // rc = 5.0

typedef float v3f __attribute__((ext_vector_type(3)));  // 12B, -> global_store_dwordx3

__global__ __launch_bounds__(256) void cellnl_kernel(
    const float* __restrict__ coord,
    const float* __restrict__ cell,
    float* __restrict__ out)
{
    const float L   = cell[0];          // cell = L * I; inv(cell) = diag(fl32(1/L))
    const float inv = 1.0f / L;

    // i is BLOCK-uniform: 4096 j's per i, 256 threads/block, 16 blocks per row.
    const int i = blockIdx.x >> 4;
    const int j = ((blockIdx.x & 15) << 8) + threadIdx.x;

    // frac_i: block-uniform -> scalar loads
    float fix = coord[3 * i + 0] * inv; fix -= floorf(fix);
    float fiy = coord[3 * i + 1] * inv; fiy -= floorf(fiy);
    float fiz = coord[3 * i + 2] * inv; fiz -= floorf(fiz);

    // frac_j: per-lane 12B load (dwordx3), stride 12 -> L1-resident (coord = 48 KB)
    const v3f cjv = *reinterpret_cast<const v3f*>(coord + 3 * j);
    float fjx = cjv.x * inv; fjx -= floorf(fjx);
    float fjy = cjv.y * inv; fjy -= floorf(fjy);
    float fjz = cjv.z * inv; fjz -= floorf(fjz);

    // dfrac = frac_j - frac_i; MIC shift = -round_half_even(dfrac)
    float dx = fjx - fix, dy = fjy - fiy, dz = fjz - fiz;
    const float sx = -rintf(dx), sy = -rintf(dy), sz = -rintf(dz);  // v_rndne = jnp.round
    dx += sx; dy += sy; dz += sz;
    dx *= L; dy *= L; dz *= L;                 // dfrac @ cell (diagonal)

    const float dist2 = dx * dx + dy * dy + dz * dz;
    const bool keep = (dist2 > 0.0f) && (dist2 < RC2);

    const size_t p = (size_t)i * N_ATOMS + j;

    // d2: 4B/lane, wave = 256B contiguous
    out[p] = keep ? dist2 : 0.0f;

    // shift: 12B/lane via dwordx3, wave = 768B contiguous (768 % 64 == 0)
    v3f sv;
    sv.x = keep ? sx : 0.0f;
    sv.y = keep ? sy : 0.0f;
    sv.z = keep ? sz : 0.0f;
    *reinterpret_cast<v3f*>(out + (size_t)N_ATOMS * N_ATOMS + p * 3) = sv;
}

extern "C" void kernel_launch(void* const* d_in, const int* in_sizes, int n_in,
                              void* d_out, int out_size, void* d_ws, size_t ws_size,
                              hipStream_t stream) {
    const float* coord = (const float*)d_in[0];   // [4096, 3] fp32
    const float* cell  = (const float*)d_in[1];   // [3, 3] fp32, L*I
    float* out = (float*)d_out;                    // 4096^2 + 4096^2*3 fp32

    const int blocks = N_ATOMS * (N_ATOMS / 256);  // one pair per thread, 65536 blocks
    hipLaunchKernelGGL(cellnl_kernel, dim3(blocks), dim3(256), 0, stream,
                       coord, cell, out);
}